// Round 10
// baseline (131.074 us; speedup 1.0000x reference)
//
#include <hip/hip_runtime.h>

#define NEGV -10000000000.0f
constexpr int Bn = 64, Tn = 512, Ln = 64;
constexpr int CK = 16;          // chunk length (TLP: 4 waves/SIMD, chain 15)
constexpr int NC = 32;          // number of chunks
constexpr int QP = 68;          // padded LDS row pitch (u16): zero epilogue bank conflicts
constexpr int WS = 2048;        // wsE/wsS per-batch stride (NC*64)

typedef float f32x16 __attribute__((ext_vector_type(16)));
typedef __bf16 bf16x8 __attribute__((ext_vector_type(8)));
typedef unsigned int u32;
typedef unsigned short u16;
typedef unsigned int u32x2 __attribute__((ext_vector_type(2)));

__device__ inline float waveMaxF(float v) {
#pragma unroll
    for (int off = 32; off > 0; off >>= 1)
        v = fmaxf(v, __shfl_xor(v, off, 64));
    return v;
}
__device__ inline u32 packbf(float a, float b) {
    u32 ua = __float_as_uint(a) + 0x8000u;
    u32 ub = __float_as_uint(b) + 0x8000u;
    return (ua >> 16) | (ub & 0xffff0000u);
}
// single-instruction pack: lo16 = bf16(a), hi16 = bf16(b)   (no builtin on gfx950)
__device__ inline u32 cvtpk(float a, float b) {
    u32 r;
    asm("v_cvt_pk_bf16_f32 %0, %1, %2" : "=v"(r) : "v"(a), "v"(b));
    return r;
}
// v_permlane32_swap_b32: new_x = {x(0:31)|y(0:31)}, new_y = {x(32:63)|y(32:63)}
__device__ inline void swap32(u32& x, u32& y) {
    u32x2 r = __builtin_amdgcn_permlane32_swap(x, y, false, false);
    x = r.x;
    y = r.y;
}
__device__ inline float lo16f(u32 d) { return __uint_as_float(d << 16); }
__device__ inline float hi16f(u32 d) { return __uint_as_float(d & 0xffff0000u); }

// ---- one tau step: 8 MFMA + diag-scale + C->B repack. MODE: 0=plain, 1=measure, 2=rescale
template <int MODE>
__device__ inline void tau_step(const uint4 (&Ap)[2][4], uint4 (&Bp)[4],
                                const float* __restrict__ gt, float rr,
                                float& lmax, int h) {
    const f32x16 Z = (f32x16)(0.0f);
    f32x16 acc0 = Z, acc1 = Z;
#pragma unroll
    for (int kc = 0; kc < 4; ++kc) {
        acc0 = __builtin_amdgcn_mfma_f32_32x32x16_bf16(
            __builtin_bit_cast(bf16x8, Ap[0][kc]),
            __builtin_bit_cast(bf16x8, Bp[kc]), acc0, 0, 0, 0);
        acc1 = __builtin_amdgcn_mfma_f32_32x32x16_bf16(
            __builtin_bit_cast(bf16x8, Ap[1][kc]),
            __builtin_bit_cast(bf16x8, Bp[kc]), acc1, 0, 0, 0);
    }
#pragma unroll
    for (int I = 0; I < 2; ++I) {
        u32 pp[8];
#pragma unroll
        for (int rg = 0; rg < 4; ++rg) {
            const int k0 = 32 * I + 8 * rg + 4 * h;
            float4 G = *(const float4*)&gt[k0];
            float gx = G.x, gy = G.y, gz = G.z, gw = G.w;
            if (MODE == 2) { gx *= rr; gy *= rr; gz *= rr; gw *= rr; }
            float v0 = (I ? acc1 : acc0)[4 * rg + 0] * gx;
            float v1 = (I ? acc1 : acc0)[4 * rg + 1] * gy;
            float v2 = (I ? acc1 : acc0)[4 * rg + 2] * gz;
            float v3 = (I ? acc1 : acc0)[4 * rg + 3] * gw;
            if (MODE == 1) lmax = fmaxf(lmax, fmaxf(fmaxf(v0, v1), fmaxf(v2, v3)));
            pp[2 * rg + 0] = cvtpk(v0, v1);
            pp[2 * rg + 1] = cvtpk(v2, v3);
        }
        // C-layout -> B-layout: exchange halves with the same-column mate lane.
        swap32(pp[0], pp[2]);
        swap32(pp[1], pp[3]);
        swap32(pp[4], pp[6]);
        swap32(pp[5], pp[7]);
        Bp[2 * I + 0] = make_uint4(pp[0], pp[1], pp[2], pp[3]);
        Bp[2 * I + 1] = make_uint4(pp[4], pp[5], pp[6], pp[7]);
    }
}

// ================= pre: tabulate exp(tr) once (launch-invariant) =================
// tblR[i][j] = exp(tr[i][j]) f32 ; tblT[m][k] = bf16(exp(tr[k][m])) (A-frag layout)
__global__ __launch_bounds__(64) void crf_pre(const float* __restrict__ tr,
                                              float* __restrict__ tblR,
                                              u16* __restrict__ tblT) {
    const int id = blockIdx.x * 64 + threadIdx.x;   // 0..4095
    tblR[id] = __expf(tr[id]);
    const int m = id >> 6, k = id & 63;
    float ev = __expf(tr[k * Ln + m]);
    tblT[id] = (u16)cvtpk(ev, ev);
}

// ---------------- serial matvec chunk scan (verified structure) -------------
template <bool FIRST>
__device__ void chunk_scan(const float* __restrict__ emb,
                           float* __restrict__ outb, float* uLDS,
                           const float* Ecol, float entry, int t0, int j, int len,
                           float trSj, float* aLastOut, float* aFinalOut) {
    const bool edge = (j == 0) || (j == Ln - 1);
    float emq[4];
#pragma unroll
    for (int tt = 0; tt < 4; ++tt) {
        float v = emb[(t0 + tt) * Ln + j];
        emq[tt] = edge ? NEGV : v;
    }
    float aPrev, mPrev, u;
    int tauStart;
    if (FIRST) {
        float a0 = trSj + emq[0];
        outb[t0 * Ln + j] = a0;
        aPrev = a0;
        mPrev = __shfl(a0, 1, 64);
        u = __expf(a0 - mPrev);
        tauStart = 1;
    } else {
        aPrev = entry;
        mPrev = __shfl(entry, 1, 64);
        u = __expf(entry - mPrev);
        tauStart = 0;
    }
    float aLast = *aLastOut;
#pragma unroll 4
    for (int tau = tauStart; tau < CK; ++tau) {
        const int t = t0 + tau;
        uLDS[j] = u;
        const float em_t = emq[tau & 3];
        const int tp = tau + 4;
        if (tp < CK) {
            float v = emb[(t0 + tp) * Ln + j];
            emq[tp & 3] = edge ? NEGV : v;
        }
        float mNext = __shfl(aPrev, 1, 64);
        float cf = __expf(em_t + (mPrev - mNext));
        float acc0 = 0.f, acc1 = 0.f, acc2 = 0.f, acc3 = 0.f;
        const float4* u4 = reinterpret_cast<const float4*>(uLDS);
#pragma unroll
        for (int i4 = 0; i4 < 16; ++i4) {
            float4 uv = u4[i4];
            acc0 = fmaf(uv.x, Ecol[4 * i4 + 0], acc0);
            acc1 = fmaf(uv.y, Ecol[4 * i4 + 1], acc1);
            acc2 = fmaf(uv.z, Ecol[4 * i4 + 2], acc2);
            acc3 = fmaf(uv.w, Ecol[4 * i4 + 3], acc3);
        }
        float S = (acc0 + acc1) + (acc2 + acc3);
        float lg = __logf(S);
        lg = (S > 0.f) ? lg : NEGV;
        float a_t = em_t + (mPrev + lg);
        outb[t * Ln + j] = a_t;
        if (t == len - 1) aLast = a_t;
        u = S * cf;
        aPrev = a_t;
        mPrev = mNext;
    }
    *aLastOut = aLast;
    *aFinalOut = aPrev;
}

// ================= PASS A: chunk-0 scan + transfer matrices (2 waves, col-split) =====
// CK=16 (R5 pass structure) + rolled tau loop (R8) + QP=68 pad (R7) + exp tables.
// 2048 blocks -> 8 blocks/CU -> 4 waves/SIMD; ~10 KB loop code stays I$-resident.
__global__ __launch_bounds__(128) void crf_passA(const float* __restrict__ em,
                                                 const float* __restrict__ tr,
                                                 const float* __restrict__ tblR,
                                                 const u16* __restrict__ tblT,
                                                 float* __restrict__ out,
                                                 float* __restrict__ wsE,
                                                 float* __restrict__ wsS,
                                                 u32* __restrict__ wsT) {
    const int b = blockIdx.x & 63;
    const int cix = blockIdx.x >> 6;         // 0..31
    const int J = threadIdx.x >> 6;          // wave id = column group
    const int L = threadIdx.x & 63;          // lane
    __shared__ alignas(16) float gtab[CK * 64];       // 4 KiB
    __shared__ alignas(16) u16 Qlds[64 * QP];         // 8.5 KiB, final writeback only
    __shared__ alignas(16) float uLDS[64];
    __shared__ float sLDS[2];
    __shared__ float sigLDS[2];

    if (cix == 0) {
        if (J == 1) return;                  // no barriers on this path
        float Ecol[Ln];
#pragma unroll
        for (int i = 0; i < Ln; ++i) Ecol[i] = tblR[i * Ln + L];
        const float trSj = tr[L];
        const float* emb = em + (size_t)b * Tn * Ln;
        float* outb = out + (size_t)b * Tn * Ln;
        float dummyLast = 0.f, aFinal;
        chunk_scan<true>(emb, outb, uLDS, Ecol, 0.f, 0, L, /*len*/ -1, trSj, &dummyLast, &aFinal);
        wsE[b * WS + 1 * 64 + L] = aFinal;
        return;
    }

    const int t0 = CK * cix;
    const int c31 = L & 31;
    const int h = L >> 5;

    // ---- gtab fill (8 rows per wave) with vectorized butterfly row-max
    {
        float orig[8], sv[8];
        const int tb = t0 + 8 * J;
#pragma unroll
        for (int r = 0; r < 8; ++r) {
            float v = em[((size_t)b * Tn + (tb + r)) * Ln + L];
            if (L == 0 || L == Ln - 1) v = NEGV;
            orig[r] = v;
            sv[r] = v;
        }
#pragma unroll
        for (int off = 32; off > 0; off >>= 1) {
#pragma unroll
            for (int r = 0; r < 8; ++r)
                sv[r] = fmaxf(sv[r], __shfl_xor(sv[r], off, 64));
        }
        float ssum = 0.f;
#pragma unroll
        for (int r = 0; r < 8; ++r) {
            gtab[(8 * J + r) * 64 + L] = __expf(orig[r] - sv[r]);
            ssum += sv[r];
        }
        if (L == 0) sLDS[J] = ssum;
    }
    __syncthreads();
    const float sSum = sLDS[0] + sLDS[1];

    // ---- A-frags: direct uint4 loads from bf16 table (layout matches fragment)
    uint4 Ap[2][4];
    {
        const uint4* Af = (const uint4*)tblT;
#pragma unroll
        for (int I = 0; I < 2; ++I)
#pragma unroll
            for (int kc = 0; kc < 4; ++kc)
                Ap[I][kc] = Af[(32 * I + c31) * 8 + 2 * kc + h];
    }

    // ---- Q0 = D_0 * E^T built directly into B-fragment registers
    const int n = 32 * J + c31;
    uint4 Bp[4];
    {
        const float* trn = tblR + n * Ln;
#pragma unroll
        for (int kc = 0; kc < 4; ++kc) {
            const int k0 = 16 * kc + 8 * h;
            float4 e0 = *(const float4*)&trn[k0];
            float4 e1 = *(const float4*)&trn[k0 + 4];
            float4 g0 = *(const float4*)&gtab[k0];
            float4 g1 = *(const float4*)&gtab[k0 + 4];
            Bp[kc] = make_uint4(cvtpk(e0.x * g0.x, e0.y * g0.y),
                                cvtpk(e0.z * g0.z, e0.w * g0.w),
                                cvtpk(e1.x * g1.x, e1.y * g1.y),
                                cvtpk(e1.z * g1.z, e1.w * g1.w));
        }
    }

    // ---- main loop: prologue (tau=1,2,3) + rolled 4-step bodies (tau=4..15).
    // Cadence: rescale at tau%4==0 (rr from wm measured 2 steps earlier), measure at %4==2.
    float sig_w = 0.f;
    float wm = 1.0f;
    float lmax = 0.f;
    tau_step<0>(Ap, Bp, gtab + 1 * 64, 1.f, lmax, h);   // tau=1
    lmax = 0.f;
    tau_step<1>(Ap, Bp, gtab + 2 * 64, 1.f, lmax, h);   // tau=2 (measure)
    wm = waveMaxF(lmax);
    tau_step<0>(Ap, Bp, gtab + 3 * 64, 1.f, lmax, h);   // tau=3
#pragma unroll 1
    for (int t4 = 1; t4 <= 3; ++t4) {
        const float* gt = gtab + (4 * t4) * 64;
        const float rr = 1.0f / wm;
        sig_w += __logf(wm);
        tau_step<2>(Ap, Bp, gt, rr, lmax, h);           // tau=4*t4 (rescale)
        tau_step<0>(Ap, Bp, gt + 64, 1.f, lmax, h);     // +1
        lmax = 0.f;
        tau_step<1>(Ap, Bp, gt + 128, 1.f, lmax, h);    // +2 (measure)
        wm = waveMaxF(lmax);
        tau_step<0>(Ap, Bp, gt + 192, 1.f, lmax, h);    // +3
    }

    // ---- one-time writeback of the product (uint2 stores: QP=68 rows are 8B-aligned)
#pragma unroll
    for (int kc = 0; kc < 4; ++kc) {
        u16* dst = &Qlds[n * QP + 16 * kc + 8 * h];
        *(uint2*)(dst) = make_uint2(Bp[kc].x, Bp[kc].y);
        *(uint2*)(dst + 4) = make_uint2(Bp[kc].z, Bp[kc].w);
    }

    // ---- reconcile per-wave scales, per-row normalize, store bf16 T-hat + sigma
    if (L == 0) sigLDS[J] = sSum + sig_w;
    __syncthreads();
    const float sg0 = sigLDS[0], sg1 = sigLDS[1];
    const float smax = fmaxf(sg0, sg1);
    const float fh = __expf((h ? sg1 : sg0) - smax);   // scale for this lane's n-half
    const int r = 32 * J + c31;                         // output row handled by this lane
    float rv[32];
    float lmaxr = 0.f;
#pragma unroll
    for (int i = 0; i < 32; ++i) {
        float v = __uint_as_float(((u32)Qlds[(32 * h + i) * QP + r]) << 16) * fh;
        rv[i] = v;
        lmaxr = fmaxf(lmaxr, v);
    }
    float rmax = fmaxf(lmaxr, __shfl_xor(lmaxr, 32, 64));
    float inv = (rmax > 0.f) ? 1.0f / rmax : 0.f;
    float sj = (rmax > 0.f) ? smax + __logf(rmax) : 0.f;
    u32* og = wsT + (size_t)(b * NC + cix) * 2048 + r * 32 + h * 16;
#pragma unroll
    for (int w8 = 0; w8 < 4; ++w8) {
        uint4 w;
        w.x = packbf(rv[8 * w8 + 0] * inv, rv[8 * w8 + 1] * inv);
        w.y = packbf(rv[8 * w8 + 2] * inv, rv[8 * w8 + 3] * inv);
        w.z = packbf(rv[8 * w8 + 4] * inv, rv[8 * w8 + 5] * inv);
        w.w = packbf(rv[8 * w8 + 6] * inv, rv[8 * w8 + 7] * inv);
        *(uint4*)(og + 4 * w8) = w;
    }
    if (h == 0) wsS[b * WS + cix * 64 + r] = sj;
}

// ================= PASS B: serial boundary combine (31 chunks) =================
__global__ __launch_bounds__(64) void crf_passB(const u32* __restrict__ wsT,
                                                float* __restrict__ wsE,
                                                const float* __restrict__ wsS) {
    const int b = blockIdx.x;
    const int j = threadIdx.x;
    __shared__ alignas(16) float uL[64];
    const u32* Qbase = wsT + (size_t)b * NC * 2048;

    float e = wsE[b * WS + 1 * 64 + j];
    uint4 nxt[8];
    float signxt = wsS[b * WS + 1 * 64 + j];
#pragma unroll
    for (int r = 0; r < 8; ++r) nxt[r] = *(const uint4*)(Qbase + 1 * 2048 + j * 32 + 4 * r);

    for (int c = 1; c <= NC - 2; ++c) {
        uint4 cur[8];
#pragma unroll
        for (int r = 0; r < 8; ++r) cur[r] = nxt[r];
        float sig = signxt;
        if (c < NC - 2) {
#pragma unroll
            for (int r = 0; r < 8; ++r)
                nxt[r] = *(const uint4*)(Qbase + (size_t)(c + 1) * 2048 + j * 32 + 4 * r);
            signxt = wsS[b * WS + (c + 1) * 64 + j];
        }
        float m = __shfl(e, 1, 64);
        uL[j] = __expf(e - m);
        const float4* u4 = reinterpret_cast<const float4*>(uL);
        float S = 0.f;
#pragma unroll
        for (int i4 = 0; i4 < 16; ++i4) {
            float4 uv = u4[i4];
            u32 d0 = ((const u32*)cur)[2 * i4];
            u32 d1 = ((const u32*)cur)[2 * i4 + 1];
            S = fmaf(uv.x, lo16f(d0), S);
            S = fmaf(uv.y, hi16f(d0), S);
            S = fmaf(uv.z, lo16f(d1), S);
            S = fmaf(uv.w, hi16f(d1), S);
        }
        float a;
        if (S > 0.f) a = m + sig + __logf(S);
        else a = m + NEGV + ((j == 0) ? NEGV : 0.f);
        e = a;
        wsE[b * WS + (c + 1) * 64 + j] = e;
    }
}

// ================= PASS C: per-chunk alpha recompute + logZ =================
__global__ __launch_bounds__(64) void crf_passC(const float* __restrict__ em,
                                                const float* __restrict__ tblR,
                                                const float* __restrict__ tr,
                                                const int* __restrict__ lens,
                                                float* __restrict__ out,
                                                const float* __restrict__ wsE) {
    const int b = blockIdx.x & 63;
    const int cix = 1 + (blockIdx.x >> 6);   // 1..31
    const int j = threadIdx.x;
    __shared__ alignas(16) float uLDS[64];

    float Ecol[Ln];
#pragma unroll
    for (int i = 0; i < Ln; ++i) Ecol[i] = tblR[i * Ln + j];
    const float trEj = tr[j * Ln + (Ln - 1)];
    const int len = lens[b];
    const float* emb = em + (size_t)b * Tn * Ln;
    float* outb = out + (size_t)b * Tn * Ln;
    const float entry = wsE[b * WS + cix * 64 + j];

    float aLast = 0.f, aFinal;
    chunk_scan<false>(emb, outb, uLDS, Ecol, entry, CK * cix, j, len, 0.f, &aLast, &aFinal);

    if (((len - 1) >> 4) == cix) {
        float last = aLast + trEj;
        float m2 = last;
#pragma unroll
        for (int off = 32; off > 0; off >>= 1)
            m2 = fmaxf(m2, __shfl_xor(m2, off, 64));
        float e2 = __expf(last - m2);
#pragma unroll
        for (int off = 32; off > 0; off >>= 1)
            e2 += __shfl_xor(e2, off, 64);
        if (j == 0) out[(size_t)Bn * Tn * Ln + b] = m2 + __logf(e2);
    }
}

// ================= fallback: single kernel, no workspace =================
__global__ __launch_bounds__(64) void crf_fallback(const float* __restrict__ em,
                                                   const float* __restrict__ tr,
                                                   const int* __restrict__ lens,
                                                   float* __restrict__ out) {
    const int b = blockIdx.x;
    const int j = threadIdx.x;
    __shared__ alignas(16) float uLDS[Ln];
    float E[Ln];
#pragma unroll
    for (int i = 0; i < Ln; ++i) E[i] = __expf(tr[i * Ln + j]);
    const float trSj = tr[j];
    const float trEj = tr[j * Ln + (Ln - 1)];
    const int len = lens[b];
    const bool edge = (j == 0) || (j == Ln - 1);
    const float* emb = em + (size_t)b * Tn * Ln;
    float* outb = out + (size_t)b * Tn * Ln;
    float emq[4];
#pragma unroll
    for (int tt = 0; tt < 4; ++tt) {
        float v = emb[tt * Ln + j];
        emq[tt] = edge ? NEGV : v;
    }
    float a = trSj + emq[0];
    outb[j] = a;
    float aPrev = a, aLast = a;
    float mPrev = __shfl(a, 1, 64);
    float u = __expf(a - mPrev);
#pragma unroll 4
    for (int t = 1; t < Tn; ++t) {
        uLDS[j] = u;
        const float em_t = emq[t & 3];
        const int tp = t + 4;
        if (tp < Tn) {
            float v = emb[tp * Ln + j];
            emq[tp & 3] = edge ? NEGV : v;
        }
        float mNext = __shfl(aPrev, 1, 64);
        float cf = __expf(em_t + (mPrev - mNext));
        float acc0 = 0.f, acc1 = 0.f, acc2 = 0.f, acc3 = 0.f;
        const float4* u4 = reinterpret_cast<const float4*>(uLDS);
#pragma unroll
        for (int i4 = 0; i4 < 16; ++i4) {
            float4 uv = u4[i4];
            acc0 = fmaf(uv.x, E[4 * i4 + 0], acc0);
            acc1 = fmaf(uv.y, E[4 * i4 + 1], acc1);
            acc2 = fmaf(uv.z, E[4 * i4 + 2], acc2);
            acc3 = fmaf(uv.w, E[4 * i4 + 3], acc3);
        }
        float S = (acc0 + acc1) + (acc2 + acc3);
        float lg = __logf(S);
        lg = (S > 0.f) ? lg : NEGV;
        float a_t = em_t + (mPrev + lg);
        outb[t * Ln + j] = a_t;
        if (t == len - 1) aLast = a_t;
        u = S * cf;
        aPrev = a_t;
        mPrev = mNext;
    }
    float last = aLast + trEj;
    float m2 = last;
#pragma unroll
    for (int off = 32; off > 0; off >>= 1)
        m2 = fmaxf(m2, __shfl_xor(m2, off, 64));
    float e2 = __expf(last - m2);
#pragma unroll
    for (int off = 32; off > 0; off >>= 1)
        e2 += __shfl_xor(e2, off, 64);
    if (j == 0) out[(size_t)Bn * Tn * Ln + b] = m2 + __logf(e2);
}

extern "C" void kernel_launch(void* const* d_in, const int* in_sizes, int n_in,
                              void* d_out, int out_size, void* d_ws, size_t ws_size,
                              hipStream_t stream) {
    const float* em = (const float*)d_in[0];
    const float* tr = (const float*)d_in[1];
    const int* lens = (const int*)d_in[2];
    float* out = (float*)d_out;
    // ws layout: tblR f32[4096] | tblT u16[4096] | wsE f32[64*WS] | wsS f32[64*WS] | wsT u32[64*NC*2048]
    const size_t wsNeed = (6144 + 2 * 64 * WS) * sizeof(float) + (size_t)64 * NC * 2048 * sizeof(u32);
    if (ws_size >= wsNeed) {
        float* tblR = (float*)d_ws;
        u16* tblT = (u16*)(tblR + 4096);
        float* wsE = tblR + 6144;
        float* wsS = wsE + 64 * WS;
        u32* wsT = (u32*)(wsS + 64 * WS);
        crf_pre<<<dim3(64), dim3(64), 0, stream>>>(tr, tblR, tblT);
        crf_passA<<<dim3(64 * NC), dim3(128), 0, stream>>>(em, tr, tblR, tblT, out, wsE, wsS, wsT);
        crf_passB<<<dim3(64), dim3(64), 0, stream>>>(wsT, wsE, wsS);
        crf_passC<<<dim3(64 * (NC - 1)), dim3(64), 0, stream>>>(em, tblR, tr, lens, out, wsE);
    } else {
        crf_fallback<<<dim3(Bn), dim3(64), 0, stream>>>(em, tr, lens, out);
    }
}

// Round 11
// 119.194 us; speedup vs baseline: 1.0997x; 1.0997x over previous
//
#include <hip/hip_runtime.h>

#define NEGV -10000000000.0f
constexpr int Bn = 64, Tn = 512, Ln = 64;
constexpr int CK = 32;          // chunk length
constexpr int NC = 16;          // number of chunks
constexpr int QP = 68;          // padded LDS row pitch (u16): zero epilogue bank conflicts

typedef float f32x16 __attribute__((ext_vector_type(16)));
typedef __bf16 bf16x8 __attribute__((ext_vector_type(8)));
typedef unsigned int u32;
typedef unsigned short u16;
typedef unsigned int u32x2 __attribute__((ext_vector_type(2)));

__device__ inline float waveMaxF(float v) {
#pragma unroll
    for (int off = 32; off > 0; off >>= 1)
        v = fmaxf(v, __shfl_xor(v, off, 64));
    return v;
}
__device__ inline u32 packbf(float a, float b) {
    u32 ua = __float_as_uint(a) + 0x8000u;
    u32 ub = __float_as_uint(b) + 0x8000u;
    return (ua >> 16) | (ub & 0xffff0000u);
}
// single-instruction pack: lo16 = bf16(a), hi16 = bf16(b)   (no builtin on gfx950)
__device__ inline u32 cvtpk(float a, float b) {
    u32 r;
    asm("v_cvt_pk_bf16_f32 %0, %1, %2" : "=v"(r) : "v"(a), "v"(b));
    return r;
}
// v_permlane32_swap_b32: new_x = {x(0:31)|y(0:31)}, new_y = {x(32:63)|y(32:63)}
__device__ inline void swap32(u32& x, u32& y) {
    u32x2 r = __builtin_amdgcn_permlane32_swap(x, y, false, false);
    x = r.x;
    y = r.y;
}
__device__ inline float lo16f(u32 d) { return __uint_as_float(d << 16); }
__device__ inline float hi16f(u32 d) { return __uint_as_float(d & 0xffff0000u); }

// ---- one tau step: 8 MFMA + diag-scale + C->B repack. MODE: 0=plain, 1=measure, 2=rescale
template <int MODE>
__device__ inline void tau_step(const uint4 (&Ap)[2][4], uint4 (&Bp)[4],
                                const float* __restrict__ gt, float rr,
                                float& lmax, int h) {
    const f32x16 Z = (f32x16)(0.0f);
    f32x16 acc0 = Z, acc1 = Z;
#pragma unroll
    for (int kc = 0; kc < 4; ++kc) {
        acc0 = __builtin_amdgcn_mfma_f32_32x32x16_bf16(
            __builtin_bit_cast(bf16x8, Ap[0][kc]),
            __builtin_bit_cast(bf16x8, Bp[kc]), acc0, 0, 0, 0);
        acc1 = __builtin_amdgcn_mfma_f32_32x32x16_bf16(
            __builtin_bit_cast(bf16x8, Ap[1][kc]),
            __builtin_bit_cast(bf16x8, Bp[kc]), acc1, 0, 0, 0);
    }
#pragma unroll
    for (int I = 0; I < 2; ++I) {
        u32 pp[8];
#pragma unroll
        for (int rg = 0; rg < 4; ++rg) {
            const int k0 = 32 * I + 8 * rg + 4 * h;
            float4 G = *(const float4*)&gt[k0];
            float gx = G.x, gy = G.y, gz = G.z, gw = G.w;
            if (MODE == 2) { gx *= rr; gy *= rr; gz *= rr; gw *= rr; }
            float v0 = (I ? acc1 : acc0)[4 * rg + 0] * gx;
            float v1 = (I ? acc1 : acc0)[4 * rg + 1] * gy;
            float v2 = (I ? acc1 : acc0)[4 * rg + 2] * gz;
            float v3 = (I ? acc1 : acc0)[4 * rg + 3] * gw;
            if (MODE == 1) lmax = fmaxf(lmax, fmaxf(fmaxf(v0, v1), fmaxf(v2, v3)));
            pp[2 * rg + 0] = cvtpk(v0, v1);
            pp[2 * rg + 1] = cvtpk(v2, v3);
        }
        // C-layout -> B-layout: exchange halves with the same-column mate lane.
        swap32(pp[0], pp[2]);
        swap32(pp[1], pp[3]);
        swap32(pp[4], pp[6]);
        swap32(pp[5], pp[7]);
        Bp[2 * I + 0] = make_uint4(pp[0], pp[1], pp[2], pp[3]);
        Bp[2 * I + 1] = make_uint4(pp[4], pp[5], pp[6], pp[7]);
    }
}

// ---------------- serial matvec chunk scan (round-2 verified structure) -------------
template <bool FIRST>
__device__ void chunk_scan(const float* __restrict__ emb,
                           float* __restrict__ outb, float* uLDS,
                           const float* Ecol, float entry, int t0, int j, int len,
                           float trSj, float* aLastOut, float* aFinalOut) {
    const bool edge = (j == 0) || (j == Ln - 1);
    float emq[4];
#pragma unroll
    for (int tt = 0; tt < 4; ++tt) {
        float v = emb[(t0 + tt) * Ln + j];
        emq[tt] = edge ? NEGV : v;
    }
    float aPrev, mPrev, u;
    int tauStart;
    if (FIRST) {
        float a0 = trSj + emq[0];
        outb[t0 * Ln + j] = a0;
        aPrev = a0;
        mPrev = __shfl(a0, 1, 64);
        u = __expf(a0 - mPrev);
        tauStart = 1;
    } else {
        aPrev = entry;
        mPrev = __shfl(entry, 1, 64);
        u = __expf(entry - mPrev);
        tauStart = 0;
    }
    float aLast = *aLastOut;
#pragma unroll 4
    for (int tau = tauStart; tau < CK; ++tau) {
        const int t = t0 + tau;
        uLDS[j] = u;
        const float em_t = emq[tau & 3];
        const int tp = tau + 4;
        if (tp < CK) {
            float v = emb[(t0 + tp) * Ln + j];
            emq[tp & 3] = edge ? NEGV : v;
        }
        float mNext = __shfl(aPrev, 1, 64);
        float cf = __expf(em_t + (mPrev - mNext));
        float acc0 = 0.f, acc1 = 0.f, acc2 = 0.f, acc3 = 0.f;
        const float4* u4 = reinterpret_cast<const float4*>(uLDS);
#pragma unroll
        for (int i4 = 0; i4 < 16; ++i4) {
            float4 uv = u4[i4];
            acc0 = fmaf(uv.x, Ecol[4 * i4 + 0], acc0);
            acc1 = fmaf(uv.y, Ecol[4 * i4 + 1], acc1);
            acc2 = fmaf(uv.z, Ecol[4 * i4 + 2], acc2);
            acc3 = fmaf(uv.w, Ecol[4 * i4 + 3], acc3);
        }
        float S = (acc0 + acc1) + (acc2 + acc3);
        float lg = __logf(S);
        lg = (S > 0.f) ? lg : NEGV;
        float a_t = em_t + (mPrev + lg);
        outb[t * Ln + j] = a_t;
        if (t == len - 1) aLast = a_t;
        u = S * cf;
        aPrev = a_t;
        mPrev = mNext;
    }
    *aLastOut = aLast;
    *aFinalOut = aPrev;
}

// ================= PASS A: chunk-0 scan + transfer matrices (2 waves, col-split) =========
// R7 structure; main loop restructured as prologue + ROLLED (#pragma unroll 1) loop of
// 4-step bodies. Fully-unrolled 31-step body was ~50 KB of code (> 32 KB I$) -- the
// measured source of the ~60% idle cycles that scaled with total work (R8: -10 us).
__global__ __launch_bounds__(128) void crf_passA(const float* __restrict__ em,
                                                 const float* __restrict__ tr,
                                                 float* __restrict__ out,
                                                 float* __restrict__ wsE,
                                                 float* __restrict__ wsS) {
    const int b = blockIdx.x & 63;
    const int cix = blockIdx.x >> 6;         // 0..15
    const int J = threadIdx.x >> 6;          // wave id = column group
    const int L = threadIdx.x & 63;          // lane
    __shared__ alignas(16) float gtab[CK * 64];       // 8 KiB
    __shared__ alignas(16) u16 Qlds[64 * QP];         // 8.5 KiB, final writeback only
    __shared__ alignas(16) float uLDS[64];
    __shared__ float sLDS[2];
    __shared__ float sigLDS[2];

    if (cix == 0) {
        if (J == 1) return;                  // no barriers on this path
        float Ecol[Ln];
#pragma unroll
        for (int i = 0; i < Ln; ++i) Ecol[i] = __expf(tr[i * Ln + L]);
        const float trSj = tr[L];
        const float* emb = em + (size_t)b * Tn * Ln;
        float* outb = out + (size_t)b * Tn * Ln;
        float dummyLast = 0.f, aFinal;
        chunk_scan<true>(emb, outb, uLDS, Ecol, 0.f, 0, L, /*len*/ -1, trSj, &dummyLast, &aFinal);
        wsE[b * 1024 + 1 * 64 + L] = aFinal;
        return;
    }

    const int t0 = CK * cix;
    const int c31 = L & 31;
    const int h = L >> 5;

    // ---- gtab fill (split by wave) with VECTORIZED butterfly row-max
    {
        float orig[16], sv[16];
        const int tb = t0 + 16 * J;
#pragma unroll
        for (int r = 0; r < 16; ++r) {
            float v = em[((size_t)b * Tn + (tb + r)) * Ln + L];
            if (L == 0 || L == Ln - 1) v = NEGV;
            orig[r] = v;
            sv[r] = v;
        }
#pragma unroll
        for (int off = 32; off > 0; off >>= 1) {
#pragma unroll
            for (int r = 0; r < 16; ++r)
                sv[r] = fmaxf(sv[r], __shfl_xor(sv[r], off, 64));
        }
        float ssum = 0.f;
#pragma unroll
        for (int r = 0; r < 16; ++r) {
            gtab[(16 * J + r) * 64 + L] = __expf(orig[r] - sv[r]);
            ssum += sv[r];
        }
        if (L == 0) sLDS[J] = ssum;
    }
    __syncthreads();
    const float sSum = sLDS[0] + sLDS[1];

    // ---- A-frags: A[m][k] = exp(tr[k][m]), m = 32I + c31, k = 16kc + 8h + q
    uint4 Ap[2][4];
#pragma unroll
    for (int I = 0; I < 2; ++I)
#pragma unroll
        for (int kc = 0; kc < 4; ++kc) {
            float e[8];
#pragma unroll
            for (int q = 0; q < 8; ++q) {
                int k = 16 * kc + 8 * h + q;
                e[q] = __expf(tr[k * Ln + 32 * I + c31]);
            }
            Ap[I][kc] = make_uint4(packbf(e[0], e[1]), packbf(e[2], e[3]),
                                   packbf(e[4], e[5]), packbf(e[6], e[7]));
        }

    // ---- Q0 built directly into B-fragment registers (own column n, own k-half)
    const int n = 32 * J + c31;
    uint4 Bp[4];
    {
        const float* trn = tr + n * Ln;
#pragma unroll
        for (int kc = 0; kc < 4; ++kc) {
            float v[8];
#pragma unroll
            for (int q = 0; q < 8; ++q) {
                const int k = 16 * kc + 8 * h + q;
                v[q] = __expf(trn[k]) * gtab[k];       // gtab row 0 = g0
            }
            Bp[kc] = make_uint4(cvtpk(v[0], v[1]), cvtpk(v[2], v[3]),
                                cvtpk(v[4], v[5]), cvtpk(v[6], v[7]));
        }
    }

    // ---- main loop: prologue (tau=1,2,3) + rolled 4-step bodies (tau=4..31).
    // Cadence identical to R2/R7: rescale at tau%4==0 (rr from wm measured 2 steps
    // earlier), measure at tau%4==2.
    float sig_w = 0.f;
    float wm = 1.0f;
    float lmax = 0.f;
    tau_step<0>(Ap, Bp, gtab + 1 * 64, 1.f, lmax, h);   // tau=1
    lmax = 0.f;
    tau_step<1>(Ap, Bp, gtab + 2 * 64, 1.f, lmax, h);   // tau=2 (measure)
    wm = waveMaxF(lmax);
    tau_step<0>(Ap, Bp, gtab + 3 * 64, 1.f, lmax, h);   // tau=3
#pragma unroll 1
    for (int t4 = 1; t4 <= 7; ++t4) {
        const float* gt = gtab + (4 * t4) * 64;
        const float rr = 1.0f / wm;
        sig_w += __logf(wm);
        tau_step<2>(Ap, Bp, gt, rr, lmax, h);           // tau=4*t4 (rescale)
        tau_step<0>(Ap, Bp, gt + 64, 1.f, lmax, h);     // +1
        lmax = 0.f;
        tau_step<1>(Ap, Bp, gt + 128, 1.f, lmax, h);    // +2 (measure)
        wm = waveMaxF(lmax);
        tau_step<0>(Ap, Bp, gt + 192, 1.f, lmax, h);    // +3
    }

    // ---- one-time writeback of R_31 (uint2 stores: QP=68 rows are 8B-aligned)
#pragma unroll
    for (int kc = 0; kc < 4; ++kc) {
        u16* dst = &Qlds[n * QP + 16 * kc + 8 * h];
        *(uint2*)(dst) = make_uint2(Bp[kc].x, Bp[kc].y);
        *(uint2*)(dst + 4) = make_uint2(Bp[kc].z, Bp[kc].w);
    }

    // ---- reconcile per-wave scales, per-row normalize, store bf16 T-hat + sigma
    if (L == 0) sigLDS[J] = sSum + sig_w;
    __syncthreads();
    const float sg0 = sigLDS[0], sg1 = sigLDS[1];
    const float smax = fmaxf(sg0, sg1);
    const float fh = __expf((h ? sg1 : sg0) - smax);   // scale for this lane's n-half
    const int r = 32 * J + c31;                         // output row handled by this lane
    float rv[32];
    float lmaxr = 0.f;
#pragma unroll
    for (int i = 0; i < 32; ++i) {
        float v = __uint_as_float(((u32)Qlds[(32 * h + i) * QP + r]) << 16) * fh;
        rv[i] = v;
        lmaxr = fmaxf(lmaxr, v);
    }
    float rmax = fmaxf(lmaxr, __shfl_xor(lmaxr, 32, 64));
    float inv = (rmax > 0.f) ? 1.0f / rmax : 0.f;
    float sj = (rmax > 0.f) ? smax + __logf(rmax) : 0.f;
    u32* og = (u32*)out + (size_t)b * (Tn * Ln) + (size_t)cix * (CK * Ln) + r * 32 + h * 16;
#pragma unroll
    for (int w8 = 0; w8 < 4; ++w8) {
        uint4 w;
        w.x = packbf(rv[8 * w8 + 0] * inv, rv[8 * w8 + 1] * inv);
        w.y = packbf(rv[8 * w8 + 2] * inv, rv[8 * w8 + 3] * inv);
        w.z = packbf(rv[8 * w8 + 4] * inv, rv[8 * w8 + 5] * inv);
        w.w = packbf(rv[8 * w8 + 6] * inv, rv[8 * w8 + 7] * inv);
        *(uint4*)(og + 4 * w8) = w;
    }
    if (h == 0) wsS[b * 1024 + cix * 64 + r] = sj;
}

// ================= PASS B: serial boundary combine =================
__global__ __launch_bounds__(64) void crf_passB(const float* __restrict__ out,
                                                float* __restrict__ wsE,
                                                const float* __restrict__ wsS) {
    const int b = blockIdx.x;
    const int j = threadIdx.x;
    __shared__ alignas(16) float uL[64];
    const u32* Qbase = (const u32*)out + (size_t)b * (Tn * Ln);

    float e = wsE[b * 1024 + 1 * 64 + j];
    uint4 nxt[8];
    float signxt = wsS[b * 1024 + 1 * 64 + j];
#pragma unroll
    for (int r = 0; r < 8; ++r) nxt[r] = *(const uint4*)(Qbase + 1 * (CK * Ln) + j * 32 + 4 * r);

#pragma unroll
    for (int c = 1; c <= 14; ++c) {
        uint4 cur[8];
#pragma unroll
        for (int r = 0; r < 8; ++r) cur[r] = nxt[r];
        float sig = signxt;
        if (c < 14) {
#pragma unroll
            for (int r = 0; r < 8; ++r)
                nxt[r] = *(const uint4*)(Qbase + (size_t)(c + 1) * (CK * Ln) + j * 32 + 4 * r);
            signxt = wsS[b * 1024 + (c + 1) * 64 + j];
        }
        float m = __shfl(e, 1, 64);
        uL[j] = __expf(e - m);
        const float4* u4 = reinterpret_cast<const float4*>(uL);
        float S = 0.f;
#pragma unroll
        for (int i4 = 0; i4 < 16; ++i4) {
            float4 uv = u4[i4];
            u32 d0 = ((const u32*)cur)[2 * i4];
            u32 d1 = ((const u32*)cur)[2 * i4 + 1];
            S = fmaf(uv.x, lo16f(d0), S);
            S = fmaf(uv.y, hi16f(d0), S);
            S = fmaf(uv.z, lo16f(d1), S);
            S = fmaf(uv.w, hi16f(d1), S);
        }
        float a;
        if (S > 0.f) a = m + sig + __logf(S);
        else a = m + NEGV + ((j == 0) ? NEGV : 0.f);
        e = a;
        wsE[b * 1024 + (c + 1) * 64 + j] = e;
    }
}

// ================= PASS C: per-chunk alpha recompute + logZ =================
__global__ __launch_bounds__(64) void crf_passC(const float* __restrict__ em,
                                                const float* __restrict__ tr,
                                                const int* __restrict__ lens,
                                                float* __restrict__ out,
                                                const float* __restrict__ wsE) {
    const int b = blockIdx.x & 63;
    const int cix = 1 + (blockIdx.x >> 6);   // 1..15
    const int j = threadIdx.x;
    __shared__ alignas(16) float uLDS[64];

    float Ecol[Ln];
#pragma unroll
    for (int i = 0; i < Ln; ++i) Ecol[i] = __expf(tr[i * Ln + j]);
    const float trEj = tr[j * Ln + (Ln - 1)];
    const int len = lens[b];
    const float* emb = em + (size_t)b * Tn * Ln;
    float* outb = out + (size_t)b * Tn * Ln;
    const float entry = wsE[b * 1024 + cix * 64 + j];

    float aLast = 0.f, aFinal;
    chunk_scan<false>(emb, outb, uLDS, Ecol, entry, CK * cix, j, len, 0.f, &aLast, &aFinal);

    if (((len - 1) >> 5) == cix) {
        float last = aLast + trEj;
        float m2 = last;
#pragma unroll
        for (int off = 32; off > 0; off >>= 1)
            m2 = fmaxf(m2, __shfl_xor(m2, off, 64));
        float e2 = __expf(last - m2);
#pragma unroll
        for (int off = 32; off > 0; off >>= 1)
            e2 += __shfl_xor(e2, off, 64);
        if (j == 0) out[(size_t)Bn * Tn * Ln + b] = m2 + __logf(e2);
    }
}

// ================= fallback: round-2 single kernel =================
__global__ __launch_bounds__(64) void crf_fallback(const float* __restrict__ em,
                                                   const float* __restrict__ tr,
                                                   const int* __restrict__ lens,
                                                   float* __restrict__ out) {
    const int b = blockIdx.x;
    const int j = threadIdx.x;
    __shared__ alignas(16) float uLDS[Ln];
    float E[Ln];
#pragma unroll
    for (int i = 0; i < Ln; ++i) E[i] = __expf(tr[i * Ln + j]);
    const float trSj = tr[j];
    const float trEj = tr[j * Ln + (Ln - 1)];
    const int len = lens[b];
    const bool edge = (j == 0) || (j == Ln - 1);
    const float* emb = em + (size_t)b * Tn * Ln;
    float* outb = out + (size_t)b * Tn * Ln;
    float emq[4];
#pragma unroll
    for (int tt = 0; tt < 4; ++tt) {
        float v = emb[tt * Ln + j];
        emq[tt] = edge ? NEGV : v;
    }
    float a = trSj + emq[0];
    outb[j] = a;
    float aPrev = a, aLast = a;
    float mPrev = __shfl(a, 1, 64);
    float u = __expf(a - mPrev);
#pragma unroll 4
    for (int t = 1; t < Tn; ++t) {
        uLDS[j] = u;
        const float em_t = emq[t & 3];
        const int tp = t + 4;
        if (tp < Tn) {
            float v = emb[tp * Ln + j];
            emq[tp & 3] = edge ? NEGV : v;
        }
        float mNext = __shfl(aPrev, 1, 64);
        float cf = __expf(em_t + (mPrev - mNext));
        float acc0 = 0.f, acc1 = 0.f, acc2 = 0.f, acc3 = 0.f;
        const float4* u4 = reinterpret_cast<const float4*>(uLDS);
#pragma unroll
        for (int i4 = 0; i4 < 16; ++i4) {
            float4 uv = u4[i4];
            acc0 = fmaf(uv.x, E[4 * i4 + 0], acc0);
            acc1 = fmaf(uv.y, E[4 * i4 + 1], acc1);
            acc2 = fmaf(uv.z, E[4 * i4 + 2], acc2);
            acc3 = fmaf(uv.w, E[4 * i4 + 3], acc3);
        }
        float S = (acc0 + acc1) + (acc2 + acc3);
        float lg = __logf(S);
        lg = (S > 0.f) ? lg : NEGV;
        float a_t = em_t + (mPrev + lg);
        outb[t * Ln + j] = a_t;
        if (t == len - 1) aLast = a_t;
        u = S * cf;
        aPrev = a_t;
        mPrev = mNext;
    }
    float last = aLast + trEj;
    float m2 = last;
#pragma unroll
    for (int off = 32; off > 0; off >>= 1)
        m2 = fmaxf(m2, __shfl_xor(m2, off, 64));
    float e2 = __expf(last - m2);
#pragma unroll
    for (int off = 32; off > 0; off >>= 1)
        e2 += __shfl_xor(e2, off, 64);
    if (j == 0) out[(size_t)Bn * Tn * Ln + b] = m2 + __logf(e2);
}

extern "C" void kernel_launch(void* const* d_in, const int* in_sizes, int n_in,
                              void* d_out, int out_size, void* d_ws, size_t ws_size,
                              hipStream_t stream) {
    const float* em = (const float*)d_in[0];
    const float* tr = (const float*)d_in[1];
    const int* lens = (const int*)d_in[2];
    float* out = (float*)d_out;
    const size_t wsNeed = 2u * 64 * 16 * 64 * sizeof(float);   // 512 KiB
    if (ws_size >= wsNeed) {
        float* wsE = (float*)d_ws;
        float* wsS = wsE + 64 * 16 * 64;
        crf_passA<<<dim3(1024), dim3(128), 0, stream>>>(em, tr, out, wsE, wsS);
        crf_passB<<<dim3(64), dim3(64), 0, stream>>>(out, wsE, wsS);
        crf_passC<<<dim3(960), dim3(64), 0, stream>>>(em, tr, lens, out, wsE);
    } else {
        crf_fallback<<<dim3(Bn), dim3(64), 0, stream>>>(em, tr, lens, out);
    }
}